// Round 5
// baseline (99.231 us; speedup 1.0000x reference)
//
#include <hip/hip_runtime.h>
#include <math.h>

#define NN 96
#define DD 512
#define PP 9120          // NN*(NN-1)
#define EPSF 1e-8f
#define INV_TEMP 100.0f
#define LOG2E 1.4426950408889634f
#define RT 8             // tasks (rows/cols of mma) per lse block
#define NTASK (2*PP)     // 18240
#define NBLK_T (NTASK/RT) // 2280
#define CBASE (PP/RT)    // 1140: first block index handling column tasks
#define NPBLK 1152       // prep blocks (8 pairs each = 9216)

// ws float-offset layout (no init-dependent state: poison-proof)
#define OFF_G     0        // G  = txt*img^T   [96*96]
#define OFF_GT    9216     // GT = G^T
#define OFF_WT    18432    // wt[k][l] = 1/(||t_k-t_l||+eps), diag 0
#define OFF_WM    27648
#define OFF_WST   36864    // wt * log2e
#define OFF_WSM   46080    // wm * log2e
#define OFF_WMAXS 55296    // [0..1151] per-prep-block max wt, [1152..2303] max wm

__device__ __forceinline__ void decomp(unsigned p, int& i, int& j) {
    unsigned ii = p / 95u;
    unsigned r  = p - ii * 95u;
    i = (int)ii;
    j = (int)(r + (r >= ii ? 1u : 0u));
}

__device__ __forceinline__ float rdlane(float v, int srclane) {
    return __int_as_float(__builtin_amdgcn_readlane(__float_as_int(v), srclane));
}

// K1: pair-per-wave prep. 1152 blocks x 4 waves x 2 pairs. Wave loads rows
// t_i,t_j,m_i,m_j coalesced (2 float4/lane), butterfly-reduces <t_i,m_j>,
// ||t_i-t_j||^2, ||m_i-m_j||^2. Writes G/GT/W tables + per-block Wmax partials.
__global__ __launch_bounds__(256) void prep_kernel(const float* __restrict__ txt,
                                                   const float* __restrict__ img,
                                                   float* __restrict__ ws) {
    __shared__ float wtw[4], wmw[4];
    int b = blockIdx.x, tid = threadIdx.x;
    int lane = tid & 63, wv = tid >> 6;
    const float4* T4 = (const float4*)txt;   // row stride 128 float4
    const float4* M4 = (const float4*)img;
    float bwt = 0.f, bwm = 0.f;

    #pragma unroll
    for (int q = 0; q < 2; ++q) {
        int pp = b * 8 + wv * 2 + q;         // 0..9215
        int i = pp / NN, j = pp - i * NN;
        const float4* Ti = T4 + i * 128 + 2 * lane;
        const float4* Tj = T4 + j * 128 + 2 * lane;
        const float4* Mi = M4 + i * 128 + 2 * lane;
        const float4* Mj = M4 + j * 128 + 2 * lane;
        float gij = 0.f, nt2 = 0.f, nm2 = 0.f;
        #pragma unroll
        for (int u = 0; u < 2; ++u) {
            float4 a = Ti[u], t = Tj[u], c = Mi[u], d = Mj[u];
            gij += a.x*d.x + a.y*d.y + a.z*d.z + a.w*d.w;       // <t_i, m_j>
            float d0 = a.x-t.x, d1 = a.y-t.y, d2 = a.z-t.z, d3 = a.w-t.w;
            nt2 += d0*d0 + d1*d1 + d2*d2 + d3*d3;               // ||t_i-t_j||^2
            float e0 = c.x-d.x, e1 = c.y-d.y, e2 = c.z-d.z, e3 = c.w-d.w;
            nm2 += e0*e0 + e1*e1 + e2*e2 + e3*e3;               // ||m_i-m_j||^2
        }
        #pragma unroll
        for (int off = 32; off > 0; off >>= 1) {
            gij += __shfl_xor(gij, off, 64);
            nt2 += __shfl_xor(nt2, off, 64);
            nm2 += __shfl_xor(nm2, off, 64);
        }
        float wt = 0.f, wm = 0.f;
        if (i != j) {
            wt = 1.f / (sqrtf(fmaxf(nt2, 0.f)) + EPSF);
            wm = 1.f / (sqrtf(fmaxf(nm2, 0.f)) + EPSF);
        }
        bwt = fmaxf(bwt, wt); bwm = fmaxf(bwm, wm);
        if (lane == 0) {
            int t0 = i * NN + j;
            ws[OFF_G  + t0] = gij;
            ws[OFF_GT + j * NN + i] = gij;   // mirror pair fills GT[i*NN+j]
            ws[OFF_WT  + t0] = wt;
            ws[OFF_WM  + t0] = wm;
            ws[OFF_WST + t0] = wt * LOG2E;
            ws[OFF_WSM + t0] = wm * LOG2E;
        }
    }
    if (lane == 0) { wtw[wv] = bwt; wmw[wv] = bwm; }
    __syncthreads();
    if (tid == 0) {
        ws[OFF_WMAXS + b]         = fmaxf(fmaxf(wtw[0], wtw[1]), fmaxf(wtw[2], wtw[3]));
        ws[OFF_WMAXS + NPBLK + b] = fmaxf(fmaxf(wmw[0], wmw[1]), fmaxf(wmw[2], wmw[3]));
    }
}

// K2: lse over 2280 blocks (8 tasks each). A rows live in REGISTERS during the
// sweep (a0r/a1r per task); A[k0]/A[k1] extracted via v_readlane (wave-uniform
// k0). Inner loop has ZERO LDS ops. w's prefetched one iteration ahead.
// DIAG computed in epilogue. One float atomicAdd into pre-zeroed out.
__global__ __launch_bounds__(256) void lse_kernel(const float* __restrict__ ws,
                                                  float* __restrict__ out) {
    __shared__ float A[RT * NN];
    __shared__ float M2s[RT];     // M * log2e
    __shared__ float Ms[RT];      // M
    __shared__ float wred[4][RT];
    __shared__ float cred[RT];

    int tid = threadIdx.x, lane = tid & 63, wv = tid >> 6;
    int b = blockIdx.x;
    bool is_col = (b >= CBASE);
    const float* Mat    = ws + (is_col ? OFF_GT  : OFF_G);
    const float* wself  = ws + (is_col ? OFF_WM  : OFF_WT);
    const float* wsweep = ws + (is_col ? OFF_WST : OFF_WSM);

    // Wmax: rows sweep wm (partials at NPBLK..), cols sweep wt (partials at 0..)
    const float* wmx = ws + OFF_WMAXS + (is_col ? 0 : NPBLK);
    float wl = 0.f;
    #pragma unroll
    for (int u = 0; u < 18; ++u)             // 18*64 = 1152
        wl = fmaxf(wl, wmx[lane + 64 * u]);
    #pragma unroll
    for (int off = 32; off > 0; off >>= 1)
        wl = fmaxf(wl, __shfl_xor(wl, off, 64));
    float Wmax = wl;
    int base = (b - (is_col ? CBASE : 0)) * RT;

    // wave wv builds rows 2wv, 2wv+1 of A; exact shift M = Wmax*(amax-amin)
    #pragma unroll
    for (int q = 0; q < 2; ++q) {
        int rr = 2 * wv + q;
        int i, j; decomp((unsigned)(base + rr), i, j);
        float s = INV_TEMP * wself[i * NN + j];
        const float* Mi = Mat + i * NN;
        const float* Mj = Mat + j * NN;
        float v0 = s * (Mi[lane] - Mj[lane]);
        A[rr * NN + lane] = v0;
        float vmax = v0, vmin = v0;
        if (lane < 32) {
            float v1 = s * (Mi[64 + lane] - Mj[64 + lane]);
            A[rr * NN + 64 + lane] = v1;
            vmax = fmaxf(vmax, v1); vmin = fminf(vmin, v1);
        }
        #pragma unroll
        for (int off = 32; off > 0; off >>= 1) {
            vmax = fmaxf(vmax, __shfl_xor(vmax, off, 64));
            vmin = fminf(vmin, __shfl_xor(vmin, off, 64));
        }
        if (lane == 0) {
            float M = Wmax * (vmax - vmin);
            Ms[rr] = M;
            M2s[rr] = M * LOG2E;
        }
    }
    __syncthreads();

    int l1 = (lane < 32) ? (64 + lane) : (lane - 32);
    float M2[RT], aL1[RT], aL2[RT], S[RT];
    float a0r[RT], a1r[RT];       // A rows in registers: k=lane, k=64+(lane&31)
    #pragma unroll
    for (int r = 0; r < RT; ++r) {
        M2[r] = __int_as_float(__builtin_amdgcn_readfirstlane(__float_as_int(M2s[r])));
        a0r[r] = A[r * NN + lane];
        a1r[r] = A[r * NN + 64 + (lane & 31)];
        aL1[r] = A[r * NN + l1];
        aL2[r] = A[r * NN + lane + 32];
        S[r] = 0.f;
    }

    // wave wv handles idx = wv + 4u, u=0..11; k0 = 2*idx (wave-uniform).
    // u<8 <=> k0<64 (static after unroll): A[k0],A[k1] via readlane from a0r/a1r.
    {
        int k0n = 2 * wv;
        float nw0 = wsweep[k0n * NN + lane];
        float nw1 = wsweep[(lane < 32 ? k0n : k0n + 1) * NN + l1];
        float nw2 = wsweep[(k0n + 1) * NN + lane + 32];
        #pragma unroll
        for (int u = 0; u < 12; ++u) {
            float w0 = nw0, w1 = nw1, w2 = nw2;
            if (u < 11) {
                int nk0 = 2 * (wv + 4 * (u + 1));
                nw0 = wsweep[nk0 * NN + lane];
                nw1 = wsweep[(lane < 32 ? nk0 : nk0 + 1) * NN + l1];
                nw2 = wsweep[(nk0 + 1) * NN + lane + 32];
            }
            #pragma unroll
            for (int r = 0; r < RT; ++r) {
                float akx, aky;
                if (u < 8) {
                    int sl = 2 * wv + 8 * u;
                    akx = rdlane(a0r[r], sl);
                    aky = rdlane(a0r[r], sl + 1);
                } else {
                    int sl = 2 * wv + 8 * (u - 8);
                    akx = rdlane(a1r[r], sl);
                    aky = rdlane(a1r[r], sl + 1);
                }
                float aksel = (lane < 32) ? akx : aky;
                S[r] += __builtin_amdgcn_exp2f(w0 * (akx   - a0r[r]) - M2[r])
                      + __builtin_amdgcn_exp2f(w1 * (aksel - aL1[r]) - M2[r])
                      + __builtin_amdgcn_exp2f(w2 * (aky   - aL2[r]) - M2[r]);
            }
        }
    }

    #pragma unroll
    for (int off = 32; off > 0; off >>= 1) {
        #pragma unroll
        for (int r = 0; r < RT; ++r) S[r] += __shfl_xor(S[r], off, 64);
    }
    if (lane == 0) {
        #pragma unroll
        for (int r = 0; r < RT; ++r) wred[wv][r] = S[r];
    }
    __syncthreads();

    if (tid < RT) {
        int r = tid;
        float tot = wred[0][r] + wred[1][r] + wred[2][r] + wred[3][r];
        tot -= 96.f * __builtin_amdgcn_exp2f(-M2s[r]);     // remove w=0 diagonal slots
        int i, j; decomp((unsigned)(base + r), i, j);
        float wtv = ws[OFF_WT + i * NN + j];
        float wmv = ws[OFF_WM + i * NN + j];
        float gii = ws[OFF_G + i * NN + i], gjj = ws[OFF_G + j * NN + j];
        float gij = ws[OFF_G + i * NN + j], gji = ws[OFF_G + j * NN + i];
        float dia = INV_TEMP * wtv * wmv * (gii - gij - gji + gjj);
        cred[r] = Ms[r] + logf(tot) - dia;
    }
    __syncthreads();
    if (tid == 0) {
        float c = 0.f;
        #pragma unroll
        for (int r = 0; r < RT; ++r) c += cred[r];
        atomicAdd(out, c * (1.0f / (float)NTASK));   // out pre-zeroed by harness
    }
}

extern "C" void kernel_launch(void* const* d_in, const int* in_sizes, int n_in,
                              void* d_out, int out_size, void* d_ws, size_t ws_size,
                              hipStream_t stream) {
    const float* txt = (const float*)d_in[0];
    const float* img = (const float*)d_in[1];
    float* ws = (float*)d_ws;
    prep_kernel<<<NPBLK, 256, 0, stream>>>(txt, img, ws);
    lse_kernel<<<NBLK_T, 256, 0, stream>>>(ws, (float*)d_out);
}